// Round 6
// baseline (16707.462 us; speedup 1.0000x reference)
//
#include <hip/hip_runtime.h>
#include <math.h>

#define Nn 131072
#define Ee 524288
#define HK 128               // h limb-plane row stride (shorts): h[0,100) pad[100,128)
#define WK 256               // gru weight k-stride: msg W@[0,100) | h W@[128,228), else 0

typedef __attribute__((ext_vector_type(8))) short short8;
typedef __attribute__((ext_vector_type(4))) float f32x4;
typedef unsigned short ushort_t;
typedef unsigned int uint32;

__device__ __forceinline__ f32x4 mfma16(short8 a, short8 b, f32x4 c) {
    return __builtin_amdgcn_mfma_f32_16x16x32_bf16(a, b, c, 0, 0, 0);
}

__device__ __forceinline__ uint32 rne_bf16(float x) {
    uint32 u = __float_as_uint(x);
    return (u + 0x7FFFu + ((u >> 16) & 1u)) >> 16;
}

// fp32 -> 3 bf16 limbs (hi, mid, lo). Lossless for normal fp32 (8+8+8 mantissa
// bits, Sterbenz-exact residuals); (l+m)+h reconstructs x exactly.
__device__ __forceinline__ void split3(float x, uint32& h, uint32& m, uint32& l) {
    h = rne_bf16(x);
    float hf = __uint_as_float(h << 16);
    float r1 = x - hf;
    m = rne_bf16(r1);
    float mf = __uint_as_float(m << 16);
    float r2 = r1 - mf;
    l = rne_bf16(r2);
}

__device__ __forceinline__ float limb2f(ushort_t u) {
    return __uint_as_float((uint32)u << 16);
}

// async global->LDS, 16B per lane; LDS dest = wave-uniform base + lane*16.
__device__ __forceinline__ void gl16(const ushort_t* g, ushort_t* l) {
    __builtin_amdgcn_global_load_lds(
        (const __attribute__((address_space(1))) uint32*)g,
        (__attribute__((address_space(3))) uint32*)l, 16, 0, 0);
}

// ---------------------------------------------------------------- diag / zero
__global__ void diag_kernel(float* out, float val) {
    int n = blockIdx.x * 256 + threadIdx.x;
    if (n < Nn) out[n] = (n == 0) ? val : 0.f;
}
__global__ void zero_ints(int* p, int n) {
    int i = blockIdx.x * 256 + threadIdx.x;
    if (i < n) p[i] = 0;
}
__global__ void zero_short8(ushort_t* p, long n8) {
    long i = (long)blockIdx.x * 256 + threadIdx.x;
    if (i < n8) {
        short8 zz = {0, 0, 0, 0, 0, 0, 0, 0};
        *(short8*)(p + i * 8) = zz;
    }
}

// ---------------------------------------------------------------- CSR build
__global__ void hist_kernel(const int* __restrict__ er, const int* __restrict__ ec,
                            int* __restrict__ cnt_f, int* __restrict__ cnt_b) {
    int e = blockIdx.x * 256 + threadIdx.x;
    atomicAdd(&cnt_f[er[e]], 1);
    atomicAdd(&cnt_b[ec[e]], 1);
}

// two independent scans in one launch (block 0: forward, block 1: backward)
__global__ __launch_bounds__(1024) void scan2_kernel(
    const int* __restrict__ cnt_f, const int* __restrict__ cnt_b,
    int* __restrict__ ptr_f, int* __restrict__ ptr_b, int n) {
    const int* cnt = blockIdx.x ? cnt_b : cnt_f;
    int* ptr = blockIdx.x ? ptr_b : ptr_f;
    __shared__ int sums[1024];
    int t = threadIdx.x;
    int chunk = n >> 10;
    int base = t * chunk;
    int s = 0;
    for (int i = 0; i < chunk; i++) s += cnt[base + i];
    sums[t] = s;
    __syncthreads();
    for (int off = 1; off < 1024; off <<= 1) {
        int v = (t >= off) ? sums[t - off] : 0;
        __syncthreads();
        sums[t] += v;
        __syncthreads();
    }
    int run = (t == 0) ? 0 : sums[t - 1];
    for (int i = 0; i < chunk; i++) { ptr[base + i] = run; run += cnt[base + i]; }
    if (t == 1023) ptr[n] = run;
}

// fill advances ptr in place; afterwards start(r) = (r ? ptr[r-1] : 0), end(r) = ptr[r]
__global__ void fill_kernel(const int* __restrict__ er, const int* __restrict__ ec,
                            int* __restrict__ ptr_f, int* __restrict__ ptr_b,
                            int* __restrict__ src_f, int* __restrict__ src_b) {
    int e = blockIdx.x * 256 + threadIdx.x;
    int r = er[e], c = ec[e];
    int p = atomicAdd(&ptr_f[r], 1); src_f[p] = c;
    int q = atomicAdd(&ptr_b[c], 1); src_b[q] = r;
}

// ---------------------------------------------------------------- weight prep
// GRU: Wt[c=4d+g][k], c<448 (28 tiles), k<WK=256.
// k<100: Wih[., k] (msg input), 128<=k<228: Whh[., k-128] (h input), else 0.
__global__ void prep_gru_w(const float* __restrict__ Wih, const float* __restrict__ Whh,
                           const float* __restrict__ bih, const float* __restrict__ bhh,
                           ushort_t* __restrict__ W0, ushort_t* __restrict__ W1,
                           ushort_t* __restrict__ W2, float* __restrict__ bg) {
    int gid = blockIdx.x * 256 + threadIdx.x;
    if (gid >= 448 * WK) return;
    int c = gid / WK, k = gid - c * WK;
    int d = c >> 2, g = c & 3;
    float w = 0.f;
    if (d < 100) {
        if (k < 100) {
            if (g == 0)      w = Wih[d * 100 + k];
            else if (g == 1) w = Wih[(100 + d) * 100 + k];
            else if (g == 2) w = Wih[(200 + d) * 100 + k];
        } else if (k >= 128 && k < 228) {
            int kk = k - 128;
            if (g == 0)      w = Whh[d * 100 + kk];
            else if (g == 1) w = Whh[(100 + d) * 100 + kk];
            else if (g == 3) w = Whh[(200 + d) * 100 + kk];
        }
    }
    uint32 h, m, l; split3(w, h, m, l);
    W0[gid] = (ushort_t)h; W1[gid] = (ushort_t)m; W2[gid] = (ushort_t)l;
    if (k == 0) {
        float b = 0.f;
        if (d < 100) {
            if (g == 0)      b = bih[d] + bhh[d];
            else if (g == 1) b = bih[100 + d] + bhh[100 + d];
            else if (g == 2) b = bih[200 + d];
            else             b = bhh[200 + d];
        }
        bg[c] = b;
    }
}

// msg MLP: W1t[c<64][k<128] (c=hidden col, k=h dim), W2t[c<112][k<64]
__global__ void prep_msg_w(const float* __restrict__ W1, const float* __restrict__ b1,
                           const float* __restrict__ W2, const float* __restrict__ b2,
                           ushort_t* __restrict__ A0, ushort_t* __restrict__ A1,
                           ushort_t* __restrict__ A2, float* __restrict__ b1p,
                           ushort_t* __restrict__ B0, ushort_t* __restrict__ B1,
                           ushort_t* __restrict__ B2, float* __restrict__ b2p) {
    int gid = blockIdx.x * 256 + threadIdx.x;
    if (gid < 8192) {
        int c = gid >> 7, k = gid & 127;
        float w = (c < 50 && k < 100) ? W1[k * 50 + c] : 0.f;
        uint32 h, m, l; split3(w, h, m, l);
        A0[gid] = (ushort_t)h; A1[gid] = (ushort_t)m; A2[gid] = (ushort_t)l;
        if (k == 0) b1p[c] = (c < 50) ? b1[c] : 0.f;
    } else if (gid < 8192 + 7168) {
        int t = gid - 8192;
        int c = t >> 6, k = t & 63;
        float w = (c < 100 && k < 50) ? W2[k * 100 + c] : 0.f;
        uint32 h, m, l; split3(w, h, m, l);
        B0[t] = (ushort_t)h; B1[t] = (ushort_t)m; B2[t] = (ushort_t)l;
        if (k == 0) b2p[c] = (c < 100) ? b2[c] : 0.f;
    }
}

// ---------------------------------------------------------------- init h
// h0 = feat @ init_W + b, split to limbs at k in [0,100) of the h planes.
__global__ void init_h_kernel(const float* __restrict__ feat, const float* __restrict__ W,
                              const float* __restrict__ b,
                              ushort_t* __restrict__ H0, ushort_t* __restrict__ H1,
                              ushort_t* __restrict__ H2) {
    int gid = blockIdx.x * 256 + threadIdx.x;   // N*100
    if (gid >= Nn * 100) return;
    int n = gid / 100, d = gid - n * 100;
    float acc = b[d];
#pragma unroll
    for (int k = 0; k < 4; k++) acc += feat[n * 4 + k] * W[k * 100 + d];
    uint32 h, m, l; split3(acc, h, m, l);
    size_t a = (size_t)n * HK + d;
    H0[a] = (ushort_t)h; H1[a] = (ushort_t)m; H2[a] = (ushort_t)l;
}

// ---------------------------------------------------------------- msg MLP (MFMA)
// fm = relu(h @ W1 + b1) @ W2 + b2 ; computed transposed: D[c][n].
// h inputs from the h limb planes ([n][128], pad [100,128) zero).
__global__ __launch_bounds__(256, 2) void msg_mfma(
    const ushort_t* __restrict__ H0, const ushort_t* __restrict__ H1,
    const ushort_t* __restrict__ H2,
    const ushort_t* __restrict__ A0, const ushort_t* __restrict__ A1,
    const ushort_t* __restrict__ A2, const float* __restrict__ b1p,
    const ushort_t* __restrict__ B0, const ushort_t* __restrict__ B1,
    const ushort_t* __restrict__ B2, const float* __restrict__ b2p,
    float* __restrict__ fm) {
    __shared__ ushort_t C1[3][64][72];
    const int tid = threadIdx.x;
    const int u = tid >> 6;          // wave = node tile
    const int lane = tid & 63;
    const int m = lane & 15, q = lane >> 4;
    const int n0 = blockIdx.x * 64;
    const int n = n0 + u * 16 + m;

    f32x4 z = {0.f, 0.f, 0.f, 0.f};
    f32x4 a1[4] = {z, z, z, z};

    const size_t hbase = (size_t)n * HK;
    for (int kc = 0; kc < 4; kc++) {
        int kb = kc * 32 + q * 8;     // k in [0,128), in-bounds, pad is zero
        short8 f0 = *(const short8*)(H0 + hbase + kb);
        short8 f1 = *(const short8*)(H1 + hbase + kb);
        short8 f2 = *(const short8*)(H2 + hbase + kb);
#pragma unroll
        for (int t = 0; t < 4; t++) {
            int off = (t * 16 + m) * 128 + kc * 32 + q * 8;
            short8 w0 = *(const short8*)(A0 + off);
            short8 w1 = *(const short8*)(A1 + off);
            short8 w2 = *(const short8*)(A2 + off);
            a1[t] = mfma16(w0, f0, a1[t]);
            a1[t] = mfma16(w0, f1, a1[t]);
            a1[t] = mfma16(w1, f0, a1[t]);
            a1[t] = mfma16(w0, f2, a1[t]);
            a1[t] = mfma16(w2, f0, a1[t]);
            a1[t] = mfma16(w1, f1, a1[t]);
        }
    }
    // epilogue 1: relu + split -> LDS
#pragma unroll
    for (int t = 0; t < 4; t++) {
        int c0 = t * 16 + 4 * q;
        float4 bb = *(const float4*)&b1p[c0];
        float v0 = fmaxf(a1[t][0] + bb.x, 0.f);
        float v1 = fmaxf(a1[t][1] + bb.y, 0.f);
        float v2 = fmaxf(a1[t][2] + bb.z, 0.f);
        float v3 = fmaxf(a1[t][3] + bb.w, 0.f);
        uint32 h0, m0, l0, h1, m1, l1, h2, m2, l2, h3, m3, l3;
        split3(v0, h0, m0, l0); split3(v1, h1, m1, l1);
        split3(v2, h2, m2, l2); split3(v3, h3, m3, l3);
        int nl = u * 16 + m;
        *(uint2*)&C1[0][nl][c0] = make_uint2(h0 | (h1 << 16), h2 | (h3 << 16));
        *(uint2*)&C1[1][nl][c0] = make_uint2(m0 | (m1 << 16), m2 | (m3 << 16));
        *(uint2*)&C1[2][nl][c0] = make_uint2(l0 | (l1 << 16), l2 | (l3 << 16));
    }
    __syncthreads();

    f32x4 a2[7] = {z, z, z, z, z, z, z};
    for (int kc = 0; kc < 2; kc++) {
        int nl = u * 16 + m;
        short8 c0f = *(const short8*)&C1[0][nl][kc * 32 + q * 8];
        short8 c1f = *(const short8*)&C1[1][nl][kc * 32 + q * 8];
        short8 c2f = *(const short8*)&C1[2][nl][kc * 32 + q * 8];
#pragma unroll
        for (int t = 0; t < 7; t++) {
            int off = (t * 16 + m) * 64 + kc * 32 + q * 8;
            short8 w0 = *(const short8*)(B0 + off);
            short8 w1 = *(const short8*)(B1 + off);
            short8 w2 = *(const short8*)(B2 + off);
            a2[t] = mfma16(w0, c0f, a2[t]);
            a2[t] = mfma16(w0, c1f, a2[t]);
            a2[t] = mfma16(w1, c0f, a2[t]);
            a2[t] = mfma16(w0, c2f, a2[t]);
            a2[t] = mfma16(w2, c0f, a2[t]);
            a2[t] = mfma16(w1, c1f, a2[t]);
        }
    }
#pragma unroll
    for (int t = 0; t < 7; t++) {
        int c0 = t * 16 + 4 * q;
        if (c0 < 100) {
            float4 bb = *(const float4*)&b2p[c0];
            float4 o;
            o.x = a2[t][0] + bb.x; o.y = a2[t][1] + bb.y;
            o.z = a2[t][2] + bb.z; o.w = a2[t][3] + bb.w;
            *(float4*)&fm[(size_t)n * 100 + c0] = o;
        }
    }
}

// ---------------------------------------------------------------- GRU v10 (fused gather + MFMA)
// 64 rows/block, 256 threads, 2 blocks/CU (LDS exactly 80 KB).
// Phase order:
//   - issue all 4 h-chunk stages (global_load_lds, 12 ops/wave) at kernel start
//   - phase G: per-block CSR gather of msg (fp32) -> LDS tile (k 0..128)
//   - barrier (drains stages under phase G's long latency -> free)
//   - K-loop kc 0..7, NO barriers: kc<4 reads fp32 msg tile + in-register
//     split3; kc>=4 reads pre-staged h limb buffers. All LDS reads use the
//     canonical linear slot=lane pattern (v9's XOR mapping caused 2e7 bank
//     conflicts). Weights register-double-buffered from L2.
//   - epilogue: hold rebuilt from hbuf (no global re-read), gates in LDS,
//     vectorized limb store back to the h planes.
// Eliminates the standalone gather4 kernel and the msg-limb global round-trip.
typedef union {
    float t32[4][4][2][64][4];   // 32 KB  [kc][rf][half][slot=q*16+r][j]
    float sh[64][116];           // 29.7 KB epilogue scratch
} GruU;

__global__ __launch_bounds__(256, 2) void gru_mfma(
    ushort_t* __restrict__ H0, ushort_t* __restrict__ H1,
    ushort_t* __restrict__ H2,
    const float* __restrict__ fm, const int* __restrict__ ptr,
    const int* __restrict__ eidx,
    const ushort_t* __restrict__ W0, const ushort_t* __restrict__ W1,
    const ushort_t* __restrict__ W2, const float* __restrict__ bg) {
    __shared__ GruU U;
    __shared__ ushort_t hbuf[4][3][4][64][8];   // 48 KB [chunk][plane][rf][slot][8]
    const int tid = threadIdx.x;
    const int wave = tid >> 6;
    const int lane = tid & 63;
    const int m = lane & 15, q = lane >> 4;
    const int n0 = blockIdx.x * 64;

    // ---- stage h limbs k[0,128): wave w covers rows w*16..w*16+15.
    // lane i -> (row i&15, chunk i>>4); LDS slot i => K-loop read slot=lane.
    {
        const size_t src = (size_t)(n0 + wave * 16 + (lane & 15)) * HK + (lane >> 4) * 8;
#pragma unroll
        for (int s = 0; s < 4; s++) {
            gl16(H0 + src + s * 32, &hbuf[s][0][wave][0][0]);
            gl16(H1 + src + s * 32, &hbuf[s][1][wave][0][0]);
            gl16(H2 + src + s * 32, &hbuf[s][2][wave][0][0]);
        }
    }

    // ---- phase G: gather msg fp32 into U.t32 (k 0..128; k>=100 zero).
    for (int t = tid; t < 2048; t += 256) {       // 64 rows x 32 float4 chunks
        int row = t >> 5, c4 = (t & 31) * 4;
        f32x4 a4 = {0.f, 0.f, 0.f, 0.f};
        if (c4 < 100) {
            int n = n0 + row;
            int s0 = (n == 0) ? 0 : ptr[n - 1];
            int e0 = ptr[n];
            for (int i = s0; i < e0; i++) {
                float4 v = *(const float4*)&fm[(size_t)eidx[i] * 100 + c4];
                a4[0] += v.x; a4[1] += v.y; a4[2] += v.z; a4[3] += v.w;
            }
        }
        *(f32x4*)&U.t32[c4 >> 5][row >> 4][(c4 >> 2) & 1]
                       [((c4 >> 3) & 3) * 16 + (row & 15)][0] = a4;
    }
    __syncthreads();   // msg tile + all staged h limbs visible

    f32x4 z = {0.f, 0.f, 0.f, 0.f};
    f32x4 acc[7][4];
#pragma unroll
    for (int t = 0; t < 7; t++)
#pragma unroll
        for (int rf = 0; rf < 4; rf++) acc[t][rf] = z;

    int woff[7];
#pragma unroll
    for (int t = 0; t < 7; t++)
        woff[t] = ((t * 4 + wave) * 16 + m) * WK + q * 8;

#define GP(Wreg, Fr)                                               \
    _Pragma("unroll")                                              \
    for (int t = 0; t < 7; t++) {                                  \
        _Pragma("unroll")                                          \
        for (int rf = 0; rf < 4; rf++)                             \
            acc[t][rf] = mfma16(Wreg[t], Fr[rf], acc[t][rf]);      \
    }

    short8 wA[7], wB[7];
#pragma unroll
    for (int t = 0; t < 7; t++) wA[t] = *(const short8*)(W0 + woff[t]);

#pragma unroll
    for (int kc = 0; kc < 8; kc++) {
        const int ko = kc * 32;
        short8 f0[4], f1[4], f2[4];
        if (kc < 4) {
            // msg: fp32 from LDS tile, split in-register
#pragma unroll
            for (int rf = 0; rf < 4; rf++) {
                f32x4 lo = *(const f32x4*)&U.t32[kc][rf][0][lane][0];
                f32x4 hi = *(const f32x4*)&U.t32[kc][rf][1][lane][0];
                float e[8] = {lo[0], lo[1], lo[2], lo[3], hi[0], hi[1], hi[2], hi[3]};
                union { short8 s; uint32 u4[4]; } p0, p1, p2;
#pragma unroll
                for (int j = 0; j < 4; j++) {
                    uint32 ha, ma, la, hb, mb, lb;
                    split3(e[2 * j], ha, ma, la);
                    split3(e[2 * j + 1], hb, mb, lb);
                    p0.u4[j] = ha | (hb << 16);
                    p1.u4[j] = ma | (mb << 16);
                    p2.u4[j] = la | (lb << 16);
                }
                f0[rf] = p0.s; f1[rf] = p1.s; f2[rf] = p2.s;
            }
        } else {
            const int b = kc - 4;
#pragma unroll
            for (int rf = 0; rf < 4; rf++) {
                f0[rf] = *(const short8*)&hbuf[b][0][rf][lane][0];
                f1[rf] = *(const short8*)&hbuf[b][1][rf][lane][0];
                f2[rf] = *(const short8*)&hbuf[b][2][rf][lane][0];
            }
        }

        if ((kc & 1) == 0) {           // W0 currently in wA
#pragma unroll
            for (int t = 0; t < 7; t++) wB[t] = *(const short8*)(W1 + woff[t] + ko);
            GP(wA, f0); GP(wA, f1); GP(wA, f2);          // W0 products
#pragma unroll
            for (int t = 0; t < 7; t++) wA[t] = *(const short8*)(W2 + woff[t] + ko);
            GP(wB, f0); GP(wB, f1);                      // W1 products
            if (kc < 7) {
#pragma unroll
                for (int t = 0; t < 7; t++) wB[t] = *(const short8*)(W0 + woff[t] + ko + 32);
            }
            GP(wA, f0);                                  // W2 product
        } else {                        // W0 currently in wB
#pragma unroll
            for (int t = 0; t < 7; t++) wA[t] = *(const short8*)(W1 + woff[t] + ko);
            GP(wB, f0); GP(wB, f1); GP(wB, f2);          // W0 products
#pragma unroll
            for (int t = 0; t < 7; t++) wB[t] = *(const short8*)(W2 + woff[t] + ko);
            GP(wA, f0); GP(wA, f1);                      // W1 products
            if (kc < 7) {
#pragma unroll
                for (int t = 0; t < 7; t++) wA[t] = *(const short8*)(W0 + woff[t] + ko + 32);
            }
            GP(wB, f0);                                  // W2 product
        }
    }
#undef GP

    __syncthreads();   // all waves past K-loop (msg tile / hbuf reads done)

    // ---- epilogue phase A: hold from staged hbuf -> U.sh (fp32)
#pragma unroll
    for (int p4 = 0; p4 < 4; p4++) {
        int ix = tid + p4 * 256;          // 1024 slots: 64 rows x 16 chunks
        int row = ix >> 4, c = ix & 15;
        if (c < 13) {                     // k [0,104); [100,104) limbs are 0
            int bb = c >> 2, cc = c & 3, sl = cc * 16 + (row & 15), rg = row >> 4;
            union { short8 s; ushort_t u[8]; } a0, a1, a2;
            a0.s = *(const short8*)&hbuf[bb][0][rg][sl][0];
            a1.s = *(const short8*)&hbuf[bb][1][rg][sl][0];
            a2.s = *(const short8*)&hbuf[bb][2][rg][sl][0];
#pragma unroll
            for (int j = 0; j < 8; j++)
                U.sh[row][c * 8 + j] =
                    (limb2f(a2.u[j]) + limb2f(a1.u[j])) + limb2f(a0.u[j]);
        }
    }
    __syncthreads();

    // ---- epilogue phase B: gates (each (row,d) owned by exactly one thread)
#pragma unroll
    for (int t = 0; t < 7; t++) {
        const int ct = t * 4 + wave;        // 0..27
        const int d = ct * 4 + q;           // 0..111
        if (d < 100) {
            float4 b4 = *(const float4*)&bg[ct * 16 + 4 * q];
#pragma unroll
            for (int rf = 0; rf < 4; rf++) {
                int row = rf * 16 + m;
                float hold = U.sh[row][d];
                float rp = acc[t][rf][0] + b4.x;
                float zp = acc[t][rf][1] + b4.y;
                float np = acc[t][rf][2] + b4.z;
                float hh = acc[t][rf][3] + b4.w;
                float rr = 1.f / (1.f + __expf(-rp));
                float zz = 1.f / (1.f + __expf(-zp));
                float nw = tanhf(np + rr * hh);
                U.sh[row][d] = (1.f - zz) * nw + zz * hold;
            }
        }
    }
    __syncthreads();

    // ---- epilogue phase C: split + vectorized 16B limb stores to h planes
#pragma unroll
    for (int p4 = 0; p4 < 4; p4++) {
        int ix = tid + p4 * 256;
        int row = ix >> 4, c = ix & 15;
        if (c < 13) {
            size_t g = (size_t)(n0 + row) * HK + c * 8;
            union { short8 s; uint32 u4[4]; } o0, o1, o2;
#pragma unroll
            for (int jj = 0; jj < 4; jj++) {
                float ea = U.sh[row][c * 8 + 2 * jj];
                float eb = U.sh[row][c * 8 + 2 * jj + 1];
                uint32 ha, ma, la, hb, mb, lb;
                split3(ea, ha, ma, la);
                split3(eb, hb, mb, lb);
                o0.u4[jj] = ha | (hb << 16);
                o1.u4[jj] = ma | (mb << 16);
                o2.u4[jj] = la | (lb << 16);
            }
            *(short8*)(H0 + g) = o0.s;
            *(short8*)(H1 + g) = o1.s;
            *(short8*)(H2 + g) = o2.s;
        }
    }
}

// ---------------------------------------------------------------- classifier
__global__ __launch_bounds__(256) void classifier(
    const ushort_t* __restrict__ H0, const ushort_t* __restrict__ H1,
    const ushort_t* __restrict__ H2, const float* __restrict__ W1,
    const float* __restrict__ b1, const float* __restrict__ W2,
    const float* __restrict__ b2, float* __restrict__ out) {
    __shared__ float Wc[3128];   // [3000,3128) zero pad: k in [100,104) rows
    __shared__ float bc[30];
    __shared__ float w2[30];
    int tid = threadIdx.x;
    for (int i = tid; i < 3128; i += 256) Wc[i] = (i < 3000) ? W1[i] : 0.f;
    if (tid < 30) { bc[tid] = b1[tid]; w2[tid] = W2[tid]; }
    __syncthreads();
    int n = blockIdx.x * 256 + tid;
    float a[30];
#pragma unroll
    for (int j = 0; j < 30; j++) a[j] = bc[j];
    const size_t base = (size_t)n * HK;
    for (int k8 = 0; k8 < 13; k8++) {     // k in [0,104); [100,104) limbs are 0
        int k0 = k8 * 8;
        union { short8 s; ushort_t u[8]; } h0, h1, h2;
        h0.s = *(const short8*)(H0 + base + k0);
        h1.s = *(const short8*)(H1 + base + k0);
        h2.s = *(const short8*)(H2 + base + k0);
#pragma unroll
        for (int jj = 0; jj < 8; jj++) {
            float hv = (limb2f(h2.u[jj]) + limb2f(h1.u[jj])) + limb2f(h0.u[jj]);
#pragma unroll
            for (int j = 0; j < 30; j++) a[j] = fmaf(hv, Wc[(k0 + jj) * 30 + j], a[j]);
        }
    }
    float s = b2[0];
#pragma unroll
    for (int j = 0; j < 30; j++) s = fmaf(fmaxf(a[j], 0.f), w2[j], s);
    out[n] = s;
}

// ---------------------------------------------------------------- launch
extern "C" void kernel_launch(void* const* d_in, const int* in_sizes, int n_in,
                              void* d_out, int out_size, void* d_ws, size_t ws_size,
                              hipStream_t stream) {
    const float* feat     = (const float*)d_in[0];
    const int*   er       = (const int*)d_in[1];
    const int*   ec       = (const int*)d_in[2];
    const float* init_W   = (const float*)d_in[3];
    const float* init_b   = (const float*)d_in[4];
    const float* fmsg_W1  = (const float*)d_in[5];
    const float* fmsg_b1  = (const float*)d_in[6];
    const float* fmsg_W2  = (const float*)d_in[7];
    const float* fmsg_b2  = (const float*)d_in[8];
    const float* bmsg_W1  = (const float*)d_in[9];
    const float* bmsg_b1  = (const float*)d_in[10];
    const float* bmsg_W2  = (const float*)d_in[11];
    const float* bmsg_b2  = (const float*)d_in[12];
    const float* fgru_Wih = (const float*)d_in[13];
    const float* fgru_Whh = (const float*)d_in[14];
    const float* fgru_bih = (const float*)d_in[15];
    const float* fgru_bhh = (const float*)d_in[16];
    const float* bgru_Wih = (const float*)d_in[17];
    const float* bgru_Whh = (const float*)d_in[18];
    const float* bgru_bih = (const float*)d_in[19];
    const float* bgru_bhh = (const float*)d_in[20];
    const float* cls_W1   = (const float*)d_in[21];
    const float* cls_b1   = (const float*)d_in[22];
    const float* cls_W2   = (const float*)d_in[23];
    const float* cls_b2   = (const float*)d_in[24];
    float* out = (float*)d_out;

    // Workspace budget (256 MiB hard limit):
    //   fm           52.43 MB
    //   h limb planes 100.66 MB (3 x (Nn*128+64) shorts)
    //   gru weights  1.65 MB (448x256 x3 x2), msg weights 0.19 MB
    //   CSR ints     6.29 MB
    //   total       ~161.2 MB  OK
    float* ws = (float*)d_ws;
    size_t o = 0;
    float* fm = ws + o; o += (size_t)Nn * 100;            // [N][100] fp32

    const size_t PL = (size_t)Nn * HK + 64;               // h plane size (shorts)
    ushort_t* us = (ushort_t*)(ws + o);
    size_t uo = 0;
    ushort_t* H0 = us + uo; uo += PL;
    ushort_t* H1 = us + uo; uo += PL;
    ushort_t* H2 = us + uo; uo += PL;
    ushort_t* fWg0 = us + uo; uo += 448 * WK;
    ushort_t* fWg1 = us + uo; uo += 448 * WK;
    ushort_t* fWg2 = us + uo; uo += 448 * WK;
    ushort_t* bWg0 = us + uo; uo += 448 * WK;
    ushort_t* bWg1 = us + uo; uo += 448 * WK;
    ushort_t* bWg2 = us + uo; uo += 448 * WK;
    ushort_t* fA0 = us + uo; uo += 8192;
    ushort_t* fA1 = us + uo; uo += 8192;
    ushort_t* fA2 = us + uo; uo += 8192;
    ushort_t* bA0 = us + uo; uo += 8192;
    ushort_t* bA1 = us + uo; uo += 8192;
    ushort_t* bA2 = us + uo; uo += 8192;
    ushort_t* fB0 = us + uo; uo += 7168;
    ushort_t* fB1 = us + uo; uo += 7168;
    ushort_t* fB2 = us + uo; uo += 7168;
    ushort_t* bB0 = us + uo; uo += 7168;
    ushort_t* bB1 = us + uo; uo += 7168;
    ushort_t* bB2 = us + uo; uo += 7168;     // uo even
    o += uo / 2;

    float* bgf  = ws + o; o += 448;
    float* bgb  = ws + o; o += 448;
    float* b1pf = ws + o; o += 64;
    float* b1pb = ws + o; o += 64;
    float* b2pf = ws + o; o += 112;
    float* b2pb = ws + o; o += 112;

    int* iws   = (int*)(ws + o);
    int* ptr_f = iws;                       // N+1
    int* ptr_b = ptr_f + (Nn + 1);          // N+1
    int* cnt   = ptr_b + (Nn + 1);          // 2N
    int* cnt_f = cnt;
    int* cnt_b = cnt + Nn;
    int* src_f = cnt + 2 * (size_t)Nn;      // E
    int* src_b = src_f + Ee;                // E

    size_t need = o * sizeof(float) +
                  (size_t)(2 * (Nn + 1) + 2 * Nn + 2 * Ee) * sizeof(int);
    if (ws_size < need) {
        diag_kernel<<<(Nn + 255) / 256, 256, 0, stream>>>(out, (float)ws_size);
        return;
    }

    // zero h limb planes once (pads [100,128) must stay 0; tail pad)
    {
        long n8 = (long)(3 * PL / 8);
        zero_short8<<<(int)((n8 + 255) / 256), 256, 0, stream>>>(H0, n8);
    }

    // CSR build
    zero_ints<<<(2 * Nn + 255) / 256, 256, 0, stream>>>(cnt, 2 * Nn);
    hist_kernel<<<Ee / 256, 256, 0, stream>>>(er, ec, cnt_f, cnt_b);
    scan2_kernel<<<2, 1024, 0, stream>>>(cnt_f, cnt_b, ptr_f, ptr_b, Nn);
    fill_kernel<<<Ee / 256, 256, 0, stream>>>(er, ec, ptr_f, ptr_b, src_f, src_b);

    // weight prep (split to 3 bf16 limbs)
    prep_gru_w<<<(448 * WK + 255) / 256, 256, 0, stream>>>(
        fgru_Wih, fgru_Whh, fgru_bih, fgru_bhh, fWg0, fWg1, fWg2, bgf);
    prep_gru_w<<<(448 * WK + 255) / 256, 256, 0, stream>>>(
        bgru_Wih, bgru_Whh, bgru_bih, bgru_bhh, bWg0, bWg1, bWg2, bgb);
    prep_msg_w<<<(15360 + 255) / 256, 256, 0, stream>>>(
        fmsg_W1, fmsg_b1, fmsg_W2, fmsg_b2, fA0, fA1, fA2, b1pf, fB0, fB1, fB2, b2pf);
    prep_msg_w<<<(15360 + 255) / 256, 256, 0, stream>>>(
        bmsg_W1, bmsg_b1, bmsg_W2, bmsg_b2, bA0, bA1, bA2, b1pb, bB0, bB1, bB2, b2pb);

    // h init (writes h limbs)
    init_h_kernel<<<(Nn * 100 + 255) / 256, 256, 0, stream>>>(
        feat, init_W, init_b, H0, H1, H2);

    const int gTile = Nn / 64;            // 2048 (msg)
    const int gGru  = Nn / 64;            // 2048 (fused gather+gru)

    for (int rd = 0; rd < 20; rd++) {
        msg_mfma<<<gTile, 256, 0, stream>>>(H0, H1, H2,
            fA0, fA1, fA2, b1pf, fB0, fB1, fB2, b2pf, fm);
        gru_mfma<<<gGru, 256, 0, stream>>>(H0, H1, H2, fm, ptr_f, src_f,
            fWg0, fWg1, fWg2, bgf);

        msg_mfma<<<gTile, 256, 0, stream>>>(H0, H1, H2,
            bA0, bA1, bA2, b1pb, bB0, bB1, bB2, b2pb, fm);
        gru_mfma<<<gGru, 256, 0, stream>>>(H0, H1, H2, fm, ptr_b, src_b,
            bWg0, bWg1, bWg2, bgb);
    }

    classifier<<<Nn / 256, 256, 0, stream>>>(H0, H1, H2,
        cls_W1, cls_b1, cls_W2, cls_b2, out);
}

// Round 7
// 14992.087 us; speedup vs baseline: 1.1144x; 1.1144x over previous
//
#include <hip/hip_runtime.h>
#include <math.h>

#define Nn 131072
#define Ee 524288
#define HK 128               // h/msg limb-plane row stride (shorts): data[0,100) pad[100,128)
#define WK 256               // gru weight k-stride: msg W@[0,100) | h W@[128,228), else 0

typedef __attribute__((ext_vector_type(8))) short short8;
typedef __attribute__((ext_vector_type(4))) float f32x4;
typedef unsigned short ushort_t;
typedef unsigned int uint32;

__device__ __forceinline__ f32x4 mfma16(short8 a, short8 b, f32x4 c) {
    return __builtin_amdgcn_mfma_f32_16x16x32_bf16(a, b, c, 0, 0, 0);
}

__device__ __forceinline__ uint32 rne_bf16(float x) {
    uint32 u = __float_as_uint(x);
    return (u + 0x7FFFu + ((u >> 16) & 1u)) >> 16;
}

// fp32 -> 3 bf16 limbs (hi, mid, lo). Lossless for normal fp32 (8+8+8 mantissa
// bits, Sterbenz-exact residuals); (l+m)+h reconstructs x exactly.
__device__ __forceinline__ void split3(float x, uint32& h, uint32& m, uint32& l) {
    h = rne_bf16(x);
    float hf = __uint_as_float(h << 16);
    float r1 = x - hf;
    m = rne_bf16(r1);
    float mf = __uint_as_float(m << 16);
    float r2 = r1 - mf;
    l = rne_bf16(r2);
}

__device__ __forceinline__ float limb2f(ushort_t u) {
    return __uint_as_float((uint32)u << 16);
}

// async global->LDS, 16B per lane; LDS dest = wave-uniform base + lane*16.
__device__ __forceinline__ void gl16(const ushort_t* g, ushort_t* l) {
    __builtin_amdgcn_global_load_lds(
        (const __attribute__((address_space(1))) uint32*)g,
        (__attribute__((address_space(3))) uint32*)l, 16, 0, 0);
}

// ---------------------------------------------------------------- diag / zero
__global__ void diag_kernel(float* out, float val) {
    int n = blockIdx.x * 256 + threadIdx.x;
    if (n < Nn) out[n] = (n == 0) ? val : 0.f;
}
__global__ void zero_ints(int* p, int n) {
    int i = blockIdx.x * 256 + threadIdx.x;
    if (i < n) p[i] = 0;
}
__global__ void zero_short8(ushort_t* p, long n8) {
    long i = (long)blockIdx.x * 256 + threadIdx.x;
    if (i < n8) {
        short8 zz = {0, 0, 0, 0, 0, 0, 0, 0};
        *(short8*)(p + i * 8) = zz;
    }
}

// ---------------------------------------------------------------- CSR build
__global__ void hist_kernel(const int* __restrict__ er, const int* __restrict__ ec,
                            int* __restrict__ cnt_f, int* __restrict__ cnt_b) {
    int e = blockIdx.x * 256 + threadIdx.x;
    atomicAdd(&cnt_f[er[e]], 1);
    atomicAdd(&cnt_b[ec[e]], 1);
}

// two independent scans in one launch (block 0: forward, block 1: backward).
// int4-vectorized serial phases (the scalar version was 196 us).
__global__ __launch_bounds__(1024) void scan2_kernel(
    const int* __restrict__ cnt_f, const int* __restrict__ cnt_b,
    int* __restrict__ ptr_f, int* __restrict__ ptr_b, int n) {
    const int* cnt = blockIdx.x ? cnt_b : cnt_f;
    int* ptr = blockIdx.x ? ptr_b : ptr_f;
    __shared__ int sums[1024];
    int t = threadIdx.x;
    int chunk = n >> 10;                 // 128
    int base = t * chunk;
    const int4* cp = (const int4*)(cnt + base);   // cnt is 16B-aligned
    int s = 0;
#pragma unroll 4
    for (int i = 0; i < 32; i++) {
        int4 v = cp[i];
        s += v.x + v.y + v.z + v.w;
    }
    sums[t] = s;
    __syncthreads();
    for (int off = 1; off < 1024; off <<= 1) {
        int v = (t >= off) ? sums[t - off] : 0;
        __syncthreads();
        sums[t] += v;
        __syncthreads();
    }
    int run = (t == 0) ? 0 : sums[t - 1];
    int4* pp = (int4*)(ptr + base);
#pragma unroll 4
    for (int i = 0; i < 32; i++) {
        int4 v = cp[i];
        int4 o;
        o.x = run; run += v.x;
        o.y = run; run += v.y;
        o.z = run; run += v.z;
        o.w = run; run += v.w;
        pp[i] = o;
    }
    if (t == 1023) ptr[n] = run;
}

// fill advances ptr in place; afterwards start(r) = (r ? ptr[r-1] : 0), end(r) = ptr[r]
__global__ void fill_kernel(const int* __restrict__ er, const int* __restrict__ ec,
                            int* __restrict__ ptr_f, int* __restrict__ ptr_b,
                            int* __restrict__ src_f, int* __restrict__ src_b) {
    int e = blockIdx.x * 256 + threadIdx.x;
    int r = er[e], c = ec[e];
    int p = atomicAdd(&ptr_f[r], 1); src_f[p] = c;
    int q = atomicAdd(&ptr_b[c], 1); src_b[q] = r;
}

// ---------------------------------------------------------------- weight prep
// GRU: Wt[c=4d+g][k], c<448 (28 tiles), k<WK=256.
// k<100: Wih[., k] (msg input), 128<=k<228: Whh[., k-128] (h input), else 0.
__global__ void prep_gru_w(const float* __restrict__ Wih, const float* __restrict__ Whh,
                           const float* __restrict__ bih, const float* __restrict__ bhh,
                           ushort_t* __restrict__ W0, ushort_t* __restrict__ W1,
                           ushort_t* __restrict__ W2, float* __restrict__ bg) {
    int gid = blockIdx.x * 256 + threadIdx.x;
    if (gid >= 448 * WK) return;
    int c = gid / WK, k = gid - c * WK;
    int d = c >> 2, g = c & 3;
    float w = 0.f;
    if (d < 100) {
        if (k < 100) {
            if (g == 0)      w = Wih[d * 100 + k];
            else if (g == 1) w = Wih[(100 + d) * 100 + k];
            else if (g == 2) w = Wih[(200 + d) * 100 + k];
        } else if (k >= 128 && k < 228) {
            int kk = k - 128;
            if (g == 0)      w = Whh[d * 100 + kk];
            else if (g == 1) w = Whh[(100 + d) * 100 + kk];
            else if (g == 3) w = Whh[(200 + d) * 100 + kk];
        }
    }
    uint32 h, m, l; split3(w, h, m, l);
    W0[gid] = (ushort_t)h; W1[gid] = (ushort_t)m; W2[gid] = (ushort_t)l;
    if (k == 0) {
        float b = 0.f;
        if (d < 100) {
            if (g == 0)      b = bih[d] + bhh[d];
            else if (g == 1) b = bih[100 + d] + bhh[100 + d];
            else if (g == 2) b = bih[200 + d];
            else             b = bhh[200 + d];
        }
        bg[c] = b;
    }
}

// msg MLP: W1t[c<64][k<128] (c=hidden col, k=h dim), W2t[c<112][k<64]
__global__ void prep_msg_w(const float* __restrict__ W1, const float* __restrict__ b1,
                           const float* __restrict__ W2, const float* __restrict__ b2,
                           ushort_t* __restrict__ A0, ushort_t* __restrict__ A1,
                           ushort_t* __restrict__ A2, float* __restrict__ b1p,
                           ushort_t* __restrict__ B0, ushort_t* __restrict__ B1,
                           ushort_t* __restrict__ B2, float* __restrict__ b2p) {
    int gid = blockIdx.x * 256 + threadIdx.x;
    if (gid < 8192) {
        int c = gid >> 7, k = gid & 127;
        float w = (c < 50 && k < 100) ? W1[k * 50 + c] : 0.f;
        uint32 h, m, l; split3(w, h, m, l);
        A0[gid] = (ushort_t)h; A1[gid] = (ushort_t)m; A2[gid] = (ushort_t)l;
        if (k == 0) b1p[c] = (c < 50) ? b1[c] : 0.f;
    } else if (gid < 8192 + 7168) {
        int t = gid - 8192;
        int c = t >> 6, k = t & 63;
        float w = (c < 100 && k < 50) ? W2[k * 100 + c] : 0.f;
        uint32 h, m, l; split3(w, h, m, l);
        B0[t] = (ushort_t)h; B1[t] = (ushort_t)m; B2[t] = (ushort_t)l;
        if (k == 0) b2p[c] = (c < 100) ? b2[c] : 0.f;
    }
}

// ---------------------------------------------------------------- init h
// h0 = feat @ init_W + b, split to limbs at k in [0,100) of the h planes.
__global__ void init_h_kernel(const float* __restrict__ feat, const float* __restrict__ W,
                              const float* __restrict__ b,
                              ushort_t* __restrict__ H0, ushort_t* __restrict__ H1,
                              ushort_t* __restrict__ H2) {
    int gid = blockIdx.x * 256 + threadIdx.x;   // N*100
    if (gid >= Nn * 100) return;
    int n = gid / 100, d = gid - n * 100;
    float acc = b[d];
#pragma unroll
    for (int k = 0; k < 4; k++) acc += feat[n * 4 + k] * W[k * 100 + d];
    uint32 h, m, l; split3(acc, h, m, l);
    size_t a = (size_t)n * HK + d;
    H0[a] = (ushort_t)h; H1[a] = (ushort_t)m; H2[a] = (ushort_t)l;
}

// ---------------------------------------------------------------- msg MLP (MFMA)
// fm = relu(h @ W1 + b1) @ W2 + b2 ; computed transposed: D[c][n].
__global__ __launch_bounds__(256, 2) void msg_mfma(
    const ushort_t* __restrict__ H0, const ushort_t* __restrict__ H1,
    const ushort_t* __restrict__ H2,
    const ushort_t* __restrict__ A0, const ushort_t* __restrict__ A1,
    const ushort_t* __restrict__ A2, const float* __restrict__ b1p,
    const ushort_t* __restrict__ B0, const ushort_t* __restrict__ B1,
    const ushort_t* __restrict__ B2, const float* __restrict__ b2p,
    float* __restrict__ fm) {
    __shared__ ushort_t C1[3][64][72];
    const int tid = threadIdx.x;
    const int u = tid >> 6;          // wave = node tile
    const int lane = tid & 63;
    const int m = lane & 15, q = lane >> 4;
    const int n0 = blockIdx.x * 64;
    const int n = n0 + u * 16 + m;

    f32x4 z = {0.f, 0.f, 0.f, 0.f};
    f32x4 a1[4] = {z, z, z, z};

    const size_t hbase = (size_t)n * HK;
    for (int kc = 0; kc < 4; kc++) {
        int kb = kc * 32 + q * 8;     // k in [0,128), in-bounds, pad is zero
        short8 f0 = *(const short8*)(H0 + hbase + kb);
        short8 f1 = *(const short8*)(H1 + hbase + kb);
        short8 f2 = *(const short8*)(H2 + hbase + kb);
#pragma unroll
        for (int t = 0; t < 4; t++) {
            int off = (t * 16 + m) * 128 + kc * 32 + q * 8;
            short8 w0 = *(const short8*)(A0 + off);
            short8 w1 = *(const short8*)(A1 + off);
            short8 w2 = *(const short8*)(A2 + off);
            a1[t] = mfma16(w0, f0, a1[t]);
            a1[t] = mfma16(w0, f1, a1[t]);
            a1[t] = mfma16(w1, f0, a1[t]);
            a1[t] = mfma16(w0, f2, a1[t]);
            a1[t] = mfma16(w2, f0, a1[t]);
            a1[t] = mfma16(w1, f1, a1[t]);
        }
    }
    // epilogue 1: relu + split -> LDS
#pragma unroll
    for (int t = 0; t < 4; t++) {
        int c0 = t * 16 + 4 * q;
        float4 bb = *(const float4*)&b1p[c0];
        float v0 = fmaxf(a1[t][0] + bb.x, 0.f);
        float v1 = fmaxf(a1[t][1] + bb.y, 0.f);
        float v2 = fmaxf(a1[t][2] + bb.z, 0.f);
        float v3 = fmaxf(a1[t][3] + bb.w, 0.f);
        uint32 h0, m0, l0, h1, m1, l1, h2, m2, l2, h3, m3, l3;
        split3(v0, h0, m0, l0); split3(v1, h1, m1, l1);
        split3(v2, h2, m2, l2); split3(v3, h3, m3, l3);
        int nl = u * 16 + m;
        *(uint2*)&C1[0][nl][c0] = make_uint2(h0 | (h1 << 16), h2 | (h3 << 16));
        *(uint2*)&C1[1][nl][c0] = make_uint2(m0 | (m1 << 16), m2 | (m3 << 16));
        *(uint2*)&C1[2][nl][c0] = make_uint2(l0 | (l1 << 16), l2 | (l3 << 16));
    }
    __syncthreads();

    f32x4 a2[7] = {z, z, z, z, z, z, z};
    for (int kc = 0; kc < 2; kc++) {
        int nl = u * 16 + m;
        short8 c0f = *(const short8*)&C1[0][nl][kc * 32 + q * 8];
        short8 c1f = *(const short8*)&C1[1][nl][kc * 32 + q * 8];
        short8 c2f = *(const short8*)&C1[2][nl][kc * 32 + q * 8];
#pragma unroll
        for (int t = 0; t < 7; t++) {
            int off = (t * 16 + m) * 64 + kc * 32 + q * 8;
            short8 w0 = *(const short8*)(B0 + off);
            short8 w1 = *(const short8*)(B1 + off);
            short8 w2 = *(const short8*)(B2 + off);
            a2[t] = mfma16(w0, c0f, a2[t]);
            a2[t] = mfma16(w0, c1f, a2[t]);
            a2[t] = mfma16(w1, c0f, a2[t]);
            a2[t] = mfma16(w0, c2f, a2[t]);
            a2[t] = mfma16(w2, c0f, a2[t]);
            a2[t] = mfma16(w1, c1f, a2[t]);
        }
    }
#pragma unroll
    for (int t = 0; t < 7; t++) {
        int c0 = t * 16 + 4 * q;
        if (c0 < 100) {
            float4 bb = *(const float4*)&b2p[c0];
            float4 o;
            o.x = a2[t][0] + bb.x; o.y = a2[t][1] + bb.y;
            o.z = a2[t][2] + bb.z; o.w = a2[t][3] + bb.w;
            *(float4*)&fm[(size_t)n * 100 + c0] = o;
        }
    }
}

// ---------------------------------------------------------------- gather (CSR)
// Sums messages over incoming edges; stores the 3-limb split to the compact
// msg planes M* at k in [0,100) (stride HK). High occupancy hides the random
// fm-row latency (this is why the fused v10 variant regressed).
__global__ void gather4(const float* __restrict__ fm, const int* __restrict__ ptr,
                        const int* __restrict__ idx,
                        ushort_t* __restrict__ M0, ushort_t* __restrict__ M1,
                        ushort_t* __restrict__ M2) {
    int gid = blockIdx.x * 256 + threadIdx.x;   // N*25
    int n = gid / 25, qq = (gid - n * 25) * 4;
    int s = (n == 0) ? 0 : ptr[n - 1];
    int e = ptr[n];
    float4 acc = {0.f, 0.f, 0.f, 0.f};
    for (int i = s; i < e; i++) {
        float4 v = *(const float4*)&fm[(size_t)idx[i] * 100 + qq];
        acc.x += v.x; acc.y += v.y; acc.z += v.z; acc.w += v.w;
    }
    uint32 h0, m0, l0, h1, m1, l1, h2, m2, l2, h3, m3, l3;
    split3(acc.x, h0, m0, l0); split3(acc.y, h1, m1, l1);
    split3(acc.z, h2, m2, l2); split3(acc.w, h3, m3, l3);
    size_t a = (size_t)n * HK + qq;
    *(uint2*)&M0[a] = make_uint2(h0 | (h1 << 16), h2 | (h3 << 16));
    *(uint2*)&M1[a] = make_uint2(m0 | (m1 << 16), m2 | (m3 << 16));
    *(uint2*)&M2[a] = make_uint2(l0 | (l1 << 16), l2 | (l3 << 16));
}

// ---------------------------------------------------------------- GRU v11
// 64 rows/block, 256 threads (4 col-waves), 2 blocks/CU (LDS 79.1 KB).
// Pure consumer: msg limbs from M planes (gather4), h limbs from H planes.
// - h fully staged up-front via global_load_lds (48 KB, 12 gl16/wave),
//   consumed in kc 4..7 with NO barriers.
// - msg double-buffered (2 x 12 KB), 4 barriers total in kc 0..3; every
//   stage is issued >= 1 kc (~815 cyc of MFMA) before its drain.
// - All K-loop LDS reads use the linear slot=lane contiguous pattern
//   (conflict-free); epilogue phase A uses a contiguous row=lane mapping
//   (v10's mapping was stride-256B -> the 2.9e7 bank conflicts).
// - Weights register-double-buffered from L2.
typedef union {
    ushort_t mbuf[2][3][4][64][8];   // 24 KB  [buf][plane][rfgrp][slot][8]
    float    sh[64][117];            // 29.95 KB epilogue scratch (117: gcd(117,32)=1)
} GruU;

__global__ __launch_bounds__(256, 2) void gru_mfma(
    ushort_t* __restrict__ H0, ushort_t* __restrict__ H1,
    ushort_t* __restrict__ H2,
    const ushort_t* __restrict__ M0, const ushort_t* __restrict__ M1,
    const ushort_t* __restrict__ M2,
    const ushort_t* __restrict__ W0, const ushort_t* __restrict__ W1,
    const ushort_t* __restrict__ W2, const float* __restrict__ bg) {
    __shared__ ushort_t hbuf[4][3][4][64][8];   // 48 KB [chunk][plane][rfgrp][slot][8]
    __shared__ GruU U;
    const int tid = threadIdx.x;
    const int wave = tid >> 6;
    const int lane = tid & 63;
    const int m = lane & 15, q = lane >> 4;
    const int n0 = blockIdx.x * 64;

    // staging: wave w covers rows [16w,16w+16); lane i -> row 16w+(i&15),
    // k-subchunk (i>>4)*8. LDS slot i => K-loop read slot = lane (q*16+m).
    const size_t src = (size_t)(n0 + wave * 16 + (lane & 15)) * HK + ((lane >> 4) << 3);

#define STAGE_H(s)                                              \
    gl16(H0 + src + (s) * 32, &hbuf[s][0][wave][0][0]);         \
    gl16(H1 + src + (s) * 32, &hbuf[s][1][wave][0][0]);         \
    gl16(H2 + src + (s) * 32, &hbuf[s][2][wave][0][0]);
#define STAGE_M(b, c)                                           \
    gl16(M0 + src + (c) * 32, &U.mbuf[b][0][wave][0][0]);       \
    gl16(M1 + src + (c) * 32, &U.mbuf[b][1][wave][0][0]);       \
    gl16(M2 + src + (c) * 32, &U.mbuf[b][2][wave][0][0]);

    STAGE_H(0) STAGE_H(1) STAGE_H(2) STAGE_H(3)
    STAGE_M(0, 0) STAGE_M(1, 1)

    f32x4 z = {0.f, 0.f, 0.f, 0.f};
    f32x4 acc[7][4];
#pragma unroll
    for (int t = 0; t < 7; t++)
#pragma unroll
        for (int rf = 0; rf < 4; rf++) acc[t][rf] = z;

    int woff[7];
#pragma unroll
    for (int t = 0; t < 7; t++)
        woff[t] = ((t * 4 + wave) * 16 + m) * WK + q * 8;

    __syncthreads();   // drain all upfront stages

#define GP(Wreg, Fr)                                               \
    _Pragma("unroll")                                              \
    for (int t = 0; t < 7; t++) {                                  \
        _Pragma("unroll")                                          \
        for (int rf = 0; rf < 4; rf++)                             \
            acc[t][rf] = mfma16(Wreg[t], Fr[rf], acc[t][rf]);      \
    }

    short8 wA[7], wB[7];
#pragma unroll
    for (int t = 0; t < 7; t++) wA[t] = *(const short8*)(W0 + woff[t]);

#pragma unroll
    for (int kc = 0; kc < 8; kc++) {
        const int ko = kc * 32;
        short8 f0[4], f1[4], f2[4];
        if (kc < 4) {
            const int b = kc & 1;
#pragma unroll
            for (int rf = 0; rf < 4; rf++) {
                f0[rf] = *(const short8*)&U.mbuf[b][0][rf][lane][0];
                f1[rf] = *(const short8*)&U.mbuf[b][1][rf][lane][0];
                f2[rf] = *(const short8*)&U.mbuf[b][2][rf][lane][0];
            }
        } else {
            const int b = kc - 4;
#pragma unroll
            for (int rf = 0; rf < 4; rf++) {
                f0[rf] = *(const short8*)&hbuf[b][0][rf][lane][0];
                f1[rf] = *(const short8*)&hbuf[b][1][rf][lane][0];
                f2[rf] = *(const short8*)&hbuf[b][2][rf][lane][0];
            }
        }

        if ((kc & 1) == 0) {           // W0 currently in wA
#pragma unroll
            for (int t = 0; t < 7; t++) wB[t] = *(const short8*)(W1 + woff[t] + ko);
            GP(wA, f0); GP(wA, f1); GP(wA, f2);          // W0 products
#pragma unroll
            for (int t = 0; t < 7; t++) wA[t] = *(const short8*)(W2 + woff[t] + ko);
            GP(wB, f0); GP(wB, f1);                      // W1 products
            if (kc < 7) {
#pragma unroll
                for (int t = 0; t < 7; t++) wB[t] = *(const short8*)(W0 + woff[t] + ko + 32);
            }
            GP(wA, f0);                                  // W2 product
        } else {                        // W0 currently in wB
#pragma unroll
            for (int t = 0; t < 7; t++) wA[t] = *(const short8*)(W1 + woff[t] + ko);
            GP(wB, f0); GP(wB, f1); GP(wB, f2);          // W0 products
#pragma unroll
            for (int t = 0; t < 7; t++) wB[t] = *(const short8*)(W2 + woff[t] + ko);
            GP(wA, f0); GP(wA, f1);                      // W1 products
            if (kc < 7) {
#pragma unroll
                for (int t = 0; t < 7; t++) wA[t] = *(const short8*)(W0 + woff[t] + ko + 32);
            }
            GP(wB, f0);                                  // W2 product
        }

        if (kc == 0) { __syncthreads(); STAGE_M(0, 2) }       // buf0 free -> c2
        else if (kc == 1) { __syncthreads(); STAGE_M(1, 3) }  // buf1 free -> c3
        else if (kc == 2 || kc == 3) { __syncthreads(); }     // drain c3 / protect union
    }
#undef GP
#undef STAGE_H
#undef STAGE_M

    // ---- epilogue phase A: hold from staged hbuf -> U.sh (fp32).
    // Contiguous mapping: row = ix&63 (lane), c = ix>>6 -> hbuf reads are
    // 16-lane-contiguous runs (conflict-free); sh writes stride 117 (coprime 32).
#pragma unroll
    for (int p4 = 0; p4 < 4; p4++) {
        int ix = tid + p4 * 256;          // 1024 slots: 64 rows x 16 chunks
        int row = ix & 63, c = ix >> 6;
        if (c < 13) {                     // k [0,104); [100,104) limbs are 0
            int sl = ((c & 3) << 4) | (row & 15);
            union { short8 s; ushort_t u[8]; } a0, a1, a2;
            a0.s = *(const short8*)&hbuf[c >> 2][0][row >> 4][sl][0];
            a1.s = *(const short8*)&hbuf[c >> 2][1][row >> 4][sl][0];
            a2.s = *(const short8*)&hbuf[c >> 2][2][row >> 4][sl][0];
#pragma unroll
            for (int j = 0; j < 8; j++)
                U.sh[row][c * 8 + j] =
                    (limb2f(a2.u[j]) + limb2f(a1.u[j])) + limb2f(a0.u[j]);
        }
    }
    __syncthreads();

    // ---- epilogue phase B: gates (each (row,d) owned by exactly one thread)
#pragma unroll
    for (int t = 0; t < 7; t++) {
        const int ct = t * 4 + wave;        // 0..27
        const int d = ct * 4 + q;           // 0..111
        if (d < 100) {
            float4 b4 = *(const float4*)&bg[ct * 16 + 4 * q];
#pragma unroll
            for (int rf = 0; rf < 4; rf++) {
                int row = rf * 16 + m;
                float hold = U.sh[row][d];
                float rp = acc[t][rf][0] + b4.x;
                float zp = acc[t][rf][1] + b4.y;
                float np = acc[t][rf][2] + b4.z;
                float hh = acc[t][rf][3] + b4.w;
                float rr = 1.f / (1.f + __expf(-rp));
                float zz = 1.f / (1.f + __expf(-zp));
                float nw = tanhf(np + rr * hh);
                U.sh[row][d] = (1.f - zz) * nw + zz * hold;
            }
        }
    }
    __syncthreads();

    // ---- epilogue phase C: split + coalesced 16B limb stores to H planes
#pragma unroll
    for (int p4 = 0; p4 < 4; p4++) {
        int ix = tid + p4 * 256;
        int row = ix >> 4, c = ix & 15;
        if (c < 13) {
            size_t g = (size_t)(n0 + row) * HK + c * 8;
            union { short8 s; uint32 u4[4]; } o0, o1, o2;
#pragma unroll
            for (int jj = 0; jj < 4; jj++) {
                float ea = U.sh[row][c * 8 + 2 * jj];
                float eb = U.sh[row][c * 8 + 2 * jj + 1];
                uint32 ha, ma, la, hb, mb, lb;
                split3(ea, ha, ma, la);
                split3(eb, hb, mb, lb);
                o0.u4[jj] = ha | (hb << 16);
                o1.u4[jj] = ma | (mb << 16);
                o2.u4[jj] = la | (lb << 16);
            }
            *(short8*)(H0 + g) = o0.s;
            *(short8*)(H1 + g) = o1.s;
            *(short8*)(H2 + g) = o2.s;
        }
    }
}

// ---------------------------------------------------------------- classifier
__global__ __launch_bounds__(256) void classifier(
    const ushort_t* __restrict__ H0, const ushort_t* __restrict__ H1,
    const ushort_t* __restrict__ H2, const float* __restrict__ W1,
    const float* __restrict__ b1, const float* __restrict__ W2,
    const float* __restrict__ b2, float* __restrict__ out) {
    __shared__ float Wc[3128];   // [3000,3128) zero pad: k in [100,104) rows
    __shared__ float bc[30];
    __shared__ float w2[30];
    int tid = threadIdx.x;
    for (int i = tid; i < 3128; i += 256) Wc[i] = (i < 3000) ? W1[i] : 0.f;
    if (tid < 30) { bc[tid] = b1[tid]; w2[tid] = W2[tid]; }
    __syncthreads();
    int n = blockIdx.x * 256 + tid;
    float a[30];
#pragma unroll
    for (int j = 0; j < 30; j++) a[j] = bc[j];
    const size_t base = (size_t)n * HK;
    for (int k8 = 0; k8 < 13; k8++) {     // k in [0,104); [100,104) limbs are 0
        int k0 = k8 * 8;
        union { short8 s; ushort_t u[8]; } h0, h1, h2;
        h0.s = *(const short8*)(H0 + base + k0);
        h1.s = *(const short8*)(H1 + base + k0);
        h2.s = *(const short8*)(H2 + base + k0);
#pragma unroll
        for (int jj = 0; jj < 8; jj++) {
            float hv = (limb2f(h2.u[jj]) + limb2f(h1.u[jj])) + limb2f(h0.u[jj]);
#pragma unroll
            for (int j = 0; j < 30; j++) a[j] = fmaf(hv, Wc[(k0 + jj) * 30 + j], a[j]);
        }
    }
    float s = b2[0];
#pragma unroll
    for (int j = 0; j < 30; j++) s = fmaf(fmaxf(a[j], 0.f), w2[j], s);
    out[n] = s;
}

// ---------------------------------------------------------------- launch
extern "C" void kernel_launch(void* const* d_in, const int* in_sizes, int n_in,
                              void* d_out, int out_size, void* d_ws, size_t ws_size,
                              hipStream_t stream) {
    const float* feat     = (const float*)d_in[0];
    const int*   er       = (const int*)d_in[1];
    const int*   ec       = (const int*)d_in[2];
    const float* init_W   = (const float*)d_in[3];
    const float* init_b   = (const float*)d_in[4];
    const float* fmsg_W1  = (const float*)d_in[5];
    const float* fmsg_b1  = (const float*)d_in[6];
    const float* fmsg_W2  = (const float*)d_in[7];
    const float* fmsg_b2  = (const float*)d_in[8];
    const float* bmsg_W1  = (const float*)d_in[9];
    const float* bmsg_b1  = (const float*)d_in[10];
    const float* bmsg_W2  = (const float*)d_in[11];
    const float* bmsg_b2  = (const float*)d_in[12];
    const float* fgru_Wih = (const float*)d_in[13];
    const float* fgru_Whh = (const float*)d_in[14];
    const float* fgru_bih = (const float*)d_in[15];
    const float* fgru_bhh = (const float*)d_in[16];
    const float* bgru_Wih = (const float*)d_in[17];
    const float* bgru_Whh = (const float*)d_in[18];
    const float* bgru_bih = (const float*)d_in[19];
    const float* bgru_bhh = (const float*)d_in[20];
    const float* cls_W1   = (const float*)d_in[21];
    const float* cls_b1   = (const float*)d_in[22];
    const float* cls_W2   = (const float*)d_in[23];
    const float* cls_b2   = (const float*)d_in[24];
    float* out = (float*)d_out;

    // Workspace budget (256 MiB = 268.4 MB hard limit):
    //   fm            52.43 MB
    //   H+M planes   201.33 MB (6 x (Nn*128+64) shorts)
    //   weights        1.56 MB
    //   CSR ints       6.29 MB
    //   total       ~261.6 MB  OK (6.8 MB headroom)
    float* ws = (float*)d_ws;
    size_t o = 0;
    float* fm = ws + o; o += (size_t)Nn * 100;            // [N][100] fp32

    const size_t PL = (size_t)Nn * HK + 64;               // plane size (shorts)
    ushort_t* us = (ushort_t*)(ws + o);
    size_t uo = 0;
    ushort_t* H0 = us + uo; uo += PL;
    ushort_t* H1 = us + uo; uo += PL;
    ushort_t* H2 = us + uo; uo += PL;
    ushort_t* M0 = us + uo; uo += PL;
    ushort_t* M1 = us + uo; uo += PL;
    ushort_t* M2 = us + uo; uo += PL;
    ushort_t* fWg0 = us + uo; uo += 448 * WK;
    ushort_t* fWg1 = us + uo; uo += 448 * WK;
    ushort_t* fWg2 = us + uo; uo += 448 * WK;
    ushort_t* bWg0 = us + uo; uo += 448 * WK;
    ushort_t* bWg1 = us + uo; uo += 448 * WK;
    ushort_t* bWg2 = us + uo; uo += 448 * WK;
    ushort_t* fA0 = us + uo; uo += 8192;
    ushort_t* fA1 = us + uo; uo += 8192;
    ushort_t* fA2 = us + uo; uo += 8192;
    ushort_t* bA0 = us + uo; uo += 8192;
    ushort_t* bA1 = us + uo; uo += 8192;
    ushort_t* bA2 = us + uo; uo += 8192;
    ushort_t* fB0 = us + uo; uo += 7168;
    ushort_t* fB1 = us + uo; uo += 7168;
    ushort_t* fB2 = us + uo; uo += 7168;
    ushort_t* bB0 = us + uo; uo += 7168;
    ushort_t* bB1 = us + uo; uo += 7168;
    ushort_t* bB2 = us + uo; uo += 7168;     // uo even
    o += uo / 2;

    float* bgf  = ws + o; o += 448;
    float* bgb  = ws + o; o += 448;
    float* b1pf = ws + o; o += 64;
    float* b1pb = ws + o; o += 64;
    float* b2pf = ws + o; o += 112;
    float* b2pb = ws + o; o += 112;

    int* iws   = (int*)(ws + o);
    int* ptr_f = iws;                       // Nn+4 (padded for int4 alignment)
    int* ptr_b = ptr_f + (Nn + 4);          // Nn+4
    int* cnt   = ptr_b + (Nn + 4);          // 2N (16B-aligned)
    int* cnt_f = cnt;
    int* cnt_b = cnt + Nn;
    int* src_f = cnt + 2 * (size_t)Nn;      // E
    int* src_b = src_f + Ee;                // E

    size_t need = o * sizeof(float) +
                  (size_t)(2 * (Nn + 4) + 2 * Nn + 2 * Ee) * sizeof(int);
    if (ws_size < need) {
        diag_kernel<<<(Nn + 255) / 256, 256, 0, stream>>>(out, (float)ws_size);
        return;
    }

    // zero all 6 limb planes once (pads [100,128) must stay 0; tail pads)
    {
        long n8 = (long)(6 * PL / 8);
        zero_short8<<<(int)((n8 + 255) / 256), 256, 0, stream>>>(H0, n8);
    }

    // CSR build
    zero_ints<<<(2 * Nn + 255) / 256, 256, 0, stream>>>(cnt, 2 * Nn);
    hist_kernel<<<Ee / 256, 256, 0, stream>>>(er, ec, cnt_f, cnt_b);
    scan2_kernel<<<2, 1024, 0, stream>>>(cnt_f, cnt_b, ptr_f, ptr_b, Nn);
    fill_kernel<<<Ee / 256, 256, 0, stream>>>(er, ec, ptr_f, ptr_b, src_f, src_b);

    // weight prep (split to 3 bf16 limbs)
    prep_gru_w<<<(448 * WK + 255) / 256, 256, 0, stream>>>(
        fgru_Wih, fgru_Whh, fgru_bih, fgru_bhh, fWg0, fWg1, fWg2, bgf);
    prep_gru_w<<<(448 * WK + 255) / 256, 256, 0, stream>>>(
        bgru_Wih, bgru_Whh, bgru_bih, bgru_bhh, bWg0, bWg1, bWg2, bgb);
    prep_msg_w<<<(15360 + 255) / 256, 256, 0, stream>>>(
        fmsg_W1, fmsg_b1, fmsg_W2, fmsg_b2, fA0, fA1, fA2, b1pf, fB0, fB1, fB2, b2pf);
    prep_msg_w<<<(15360 + 255) / 256, 256, 0, stream>>>(
        bmsg_W1, bmsg_b1, bmsg_W2, bmsg_b2, bA0, bA1, bA2, b1pb, bB0, bB1, bB2, b2pb);

    // h init (writes h limbs)
    init_h_kernel<<<(Nn * 100 + 255) / 256, 256, 0, stream>>>(
        feat, init_W, init_b, H0, H1, H2);

    const int gTile = Nn / 64;            // 2048 (msg)
    const int gGru  = Nn / 64;            // 2048 (gru)
    const int gGath = Nn * 25 / 256;      // 12800

    for (int rd = 0; rd < 20; rd++) {
        msg_mfma<<<gTile, 256, 0, stream>>>(H0, H1, H2,
            fA0, fA1, fA2, b1pf, fB0, fB1, fB2, b2pf, fm);
        gather4<<<gGath, 256, 0, stream>>>(fm, ptr_f, src_f, M0, M1, M2);
        gru_mfma<<<gGru, 256, 0, stream>>>(H0, H1, H2, M0, M1, M2,
            fWg0, fWg1, fWg2, bgf);

        msg_mfma<<<gTile, 256, 0, stream>>>(H0, H1, H2,
            bA0, bA1, bA2, b1pb, bB0, bB1, bB2, b2pb, fm);
        gather4<<<gGath, 256, 0, stream>>>(fm, ptr_b, src_b, M0, M1, M2);
        gru_mfma<<<gGru, 256, 0, stream>>>(H0, H1, H2, M0, M1, M2,
            bWg0, bWg1, bWg2, bgb);
    }

    classifier<<<Nn / 256, 256, 0, stream>>>(H0, H1, H2,
        cls_W1, cls_b1, cls_W2, cls_b2, out);
}